// Round 2
// baseline (3373.414 us; speedup 1.0000x reference)
//
#include <hip/hip_runtime.h>
#include <hip/hip_bf16.h>

typedef __attribute__((ext_vector_type(8))) short short8;
typedef __attribute__((ext_vector_type(4))) float f32x4;

constexpr int Tt = 8192, Kd = 1024, Nd = 1024, Gn = 8;
constexpr int BM = 128, BN = 128, BK = 64;
constexpr int NKT = Kd / BK; // 16 K-steps

static __device__ __forceinline__ short f2bf(float x) {
    __hip_bfloat16 b = __float2bfloat16(x);
    return *reinterpret_cast<short*>(&b);
}

__global__ __launch_bounds__(256, 2)
void grouped_gemm_kernel(const float* __restrict__ H,
                         const float* __restrict__ W,
                         const int* __restrict__ counts,
                         float* __restrict__ out)
{
    // double-buffered LDS tiles, bf16, [row][8 chunks of 8 elems], XOR-swizzled
    __shared__ __align__(16) short As[2][BM * BK];
    __shared__ __align__(16) short Bs[2][BN * BK];

    const int tid = threadIdx.x;
    const int bid = blockIdx.x;
    // bijective XCD swizzle (512 % 8 == 0): XCD x owns 8 consecutive row-panels
    const int wg = (bid & 7) * 64 + (bid >> 3);
    const int mt = wg >> 3, nt = wg & 7;
    const int row0 = mt * BM, col0 = nt * BN;

    // expert id for this row tile (counts are multiples of BM -> no straddle)
    int g = 0;
    {
        int c = 0;
        for (int i = 0; i < Gn; ++i) { c += counts[i]; if (row0 >= c) g = i + 1; }
    }
    const float* __restrict__ Wg = W + (size_t)g * Kd * Nd;

    const int wid = tid >> 6, lane = tid & 63;
    const int wm = wid >> 1, wn = wid & 1;   // 2x2 wave grid, each wave 64x64
    const int l15 = lane & 15, l4 = lane >> 4;

    f32x4 acc[4][4];
#pragma unroll
    for (int i = 0; i < 4; ++i)
#pragma unroll
        for (int j = 0; j < 4; ++j) acc[i][j] = (f32x4)0.0f;

    // two named ping-pong staging sets (rule #20: never runtime-index these)
    f32x4 a0[4][2], a1[4][2];
    float b0[4][8], b1[4][8];

    auto load_a = [&](int kt, f32x4 (&ar)[4][2]) {
        const int kbase = kt * BK;
#pragma unroll
        for (int i = 0; i < 4; ++i) {
            const int idx = i * 256 + tid;
            const int m = idx >> 3, kc = idx & 7;     // A chunk (m, kc): 8 k-elems
            const float* p = H + (size_t)(row0 + m) * Kd + kbase + kc * 8;
            ar[i][0] = *(const f32x4*)p;
            ar[i][1] = *(const f32x4*)(p + 4);
        }
    };
    auto load_b = [&](int kt, float (&br)[4][8]) {
        const int kbase = kt * BK;
#pragma unroll
        for (int i = 0; i < 4; ++i) {
            const int idx = i * 256 + tid;
            const int kc = idx >> 7, n = idx & 127;   // B chunk (n, kc)
            const float* p = Wg + (size_t)(kbase + kc * 8) * Nd + col0 + n;
#pragma unroll
            for (int j = 0; j < 8; ++j) br[i][j] = p[(size_t)j * Nd];
        }
    };

    auto write_stage = [&](int buf, f32x4 (&ar)[4][2], float (&br)[4][8]) {
#pragma unroll
        for (int i = 0; i < 4; ++i) {
            const int idx = i * 256 + tid;
            const int m = idx >> 3, kc = idx & 7;
            short8 v;
#pragma unroll
            for (int j = 0; j < 4; ++j) v[j] = f2bf(ar[i][0][j]);
#pragma unroll
            for (int j = 0; j < 4; ++j) v[4 + j] = f2bf(ar[i][1][j]);
            *(short8*)&As[buf][m * BK + ((kc ^ (m & 7)) << 3)] = v;
        }
#pragma unroll
        for (int i = 0; i < 4; ++i) {
            const int idx = i * 256 + tid;
            const int kc = idx >> 7, n = idx & 127;
            short8 v;
#pragma unroll
            for (int j = 0; j < 8; ++j) v[j] = f2bf(br[i][j]);
            *(short8*)&Bs[buf][n * BK + ((kc ^ (n & 7)) << 3)] = v;
        }
    };

    auto compute = [&](int buf) {
#pragma unroll
        for (int ks = 0; ks < 2; ++ks) {         // two K=32 slices per BK=64
            short8 af[4], bfr[4];
#pragma unroll
            for (int mi = 0; mi < 4; ++mi) {
                const int r = wm * 64 + mi * 16 + l15;
                const int c = (ks * 4 + l4) ^ (r & 7);
                af[mi] = *(const short8*)&As[buf][r * BK + (c << 3)];
            }
#pragma unroll
            for (int ni = 0; ni < 4; ++ni) {
                const int r = wn * 64 + ni * 16 + l15;
                const int c = (ks * 4 + l4) ^ (r & 7);
                bfr[ni] = *(const short8*)&Bs[buf][r * BK + (c << 3)];
            }
#pragma unroll
            for (int mi = 0; mi < 4; ++mi)
#pragma unroll
                for (int ni = 0; ni < 4; ++ni)
                    acc[mi][ni] = __builtin_amdgcn_mfma_f32_16x16x32_bf16(
                        af[mi], bfr[ni], acc[mi][ni], 0, 0, 0);
        }
    };

    // prologue: tile0 -> buf0 via set0; tile1 in flight in set1
    load_a(0, a0); load_b(0, b0);
    write_stage(0, a0, b0);
    load_a(1, a1); load_b(1, b1);
    __syncthreads();

    // 2-deep pipelined main loop, unrolled x2 so reg-set choice is static.
    // Step kt: compute(buf kt&1); write tile kt+1 -> buf (kt+1)&1 from set (kt+1)&1;
    //          issue loads for tile kt+2 into set kt&1 (A early, B after write).
    for (int kt2 = 0; kt2 < NKT; kt2 += 2) {
        // step A (kt = kt2, buf0, free set = 0)
        if (kt2 + 2 < NKT) load_a(kt2 + 2, a0);
        compute(0);
        write_stage(1, a1, b1);                  // tile kt2+1 (always valid)
        if (kt2 + 2 < NKT) load_b(kt2 + 2, b0);
        __syncthreads();
        // step B (kt = kt2+1, buf1, free set = 1)
        if (kt2 + 3 < NKT) load_a(kt2 + 3, a1);
        compute(1);
        if (kt2 + 2 < NKT) write_stage(0, a0, b0);  // tile kt2+2
        if (kt2 + 3 < NKT) load_b(kt2 + 3, b1);
        __syncthreads();
    }

    // epilogue: C/D layout col=lane&15, row=(lane>>4)*4+reg (m89-verified)
#pragma unroll
    for (int mi = 0; mi < 4; ++mi) {
        const int rbase = row0 + wm * 64 + mi * 16 + l4 * 4;
#pragma unroll
        for (int ni = 0; ni < 4; ++ni) {
            const int c = col0 + wn * 64 + ni * 16 + l15;
#pragma unroll
            for (int r = 0; r < 4; ++r)
                out[(size_t)(rbase + r) * Nd + c] = acc[mi][ni][r];
        }
    }
}

extern "C" void kernel_launch(void* const* d_in, const int* in_sizes, int n_in,
                              void* d_out, int out_size, void* d_ws, size_t ws_size,
                              hipStream_t stream) {
    const float* H = (const float*)d_in[0];
    const float* W = (const float*)d_in[1];
    const int* counts = (const int*)d_in[2];
    float* out = (float*)d_out;
    const int grid = (Tt / BM) * (Nd / BN);  // 64 * 8 = 512 blocks
    grouped_gemm_kernel<<<grid, 256, 0, stream>>>(H, W, counts, out);
}

// Round 3
// 48.127 us; speedup vs baseline: 70.0936x; 70.0936x over previous
//
#include <hip/hip_runtime.h>
#include <hip/hip_bf16.h>
#include <stdint.h>

typedef __attribute__((ext_vector_type(8))) short short8;
typedef __attribute__((ext_vector_type(4))) float f32x4;

constexpr int Tt = 8192, Kd = 1024, Nd = 1024, Gn = 8;
constexpr int BM = 128, BN = 128, BK = 32;
constexpr int NKT = Kd / BK; // 32 K-steps

static __device__ __forceinline__ short f2bf(float x) {
    __hip_bfloat16 b = __float2bfloat16(x);
    return *reinterpret_cast<short*>(&b);
}

__global__ __launch_bounds__(256, 3)
void grouped_gemm_kernel(const float* __restrict__ H,
                         const float* __restrict__ W,
                         const int* __restrict__ counts,
                         float* __restrict__ out)
{
    // A: fp32 [m][k], filled by global_load_lds with pre-swizzled SOURCE (m173):
    //    16B granule (m,gc) holds global granule gc^(m&7).  16 KB x2.
    // B: bf16 [n][k] transposed+swizzled (granule g^(n&3)), reg-staged. 8 KB x2.
    // Total 48 KB -> 3 blocks/CU.
    __shared__ __align__(16) float Asf[2][BM * BK];
    __shared__ __align__(16) short Bss[2][BN * BK];

    const int tid = threadIdx.x;
    const int bid = blockIdx.x;
    // bijective XCD swizzle (512 % 8 == 0)
    const int wg = (bid & 7) * 64 + (bid >> 3);
    const int mt = wg >> 3, nt = wg & 7;
    const int row0 = mt * BM, col0 = nt * BN;

    // expert id (counts are multiples of 128 -> tiles never straddle experts)
    int g = 0;
    {
        int c = 0;
        for (int i = 0; i < Gn; ++i) { c += counts[i]; if (row0 >= c) g = i + 1; }
    }
    const float* __restrict__ Wg = W + (size_t)g * Kd * Nd;

    const int wid = tid >> 6, lane = tid & 63;
    const int wm = wid >> 1, wn = wid & 1;   // 2x2 wave grid, 64x64 per wave
    const int l15 = lane & 15, l4 = lane >> 4;

    f32x4 acc[4][4];
#pragma unroll
    for (int i = 0; i < 4; ++i)
#pragma unroll
        for (int j = 0; j < 4; ++j) acc[i][j] = (f32x4)0.0f;

    // single B staging set: 16 floats/thread (static indexing only)
    float breg[16];
    const int bn = tid & 127, bkh = tid >> 7;

    auto stage_a = [&](int kt, int buf) {
        const int kbase = kt * BK;
#pragma unroll
        for (int i = 0; i < 4; ++i) {
            const int q = wid * 4 + i;           // 1KB chunk id (wave-uniform)
            const int d = q * 64 + lane;         // 16B granule id in tile
            const int m = d >> 3, gc = d & 7;
            const float* src = H + (size_t)(row0 + m) * Kd + kbase + ((gc ^ (m & 7)) << 2);
            __builtin_amdgcn_global_load_lds(
                (const __attribute__((address_space(1))) uint32_t*)src,
                (__attribute__((address_space(3))) uint32_t*)(&Asf[buf][q * 256]),
                16, 0, 0);
        }
    };

    auto load_b = [&](int kt) {
        const float* p = Wg + (size_t)(kt * BK + bkh * 16) * Nd + col0 + bn;
#pragma unroll
        for (int j = 0; j < 16; ++j) breg[j] = p[(size_t)j * Nd];
    };

    auto write_b = [&](int buf) {
        short8 v0, v1;
#pragma unroll
        for (int j = 0; j < 8; ++j) { v0[j] = f2bf(breg[j]); v1[j] = f2bf(breg[8 + j]); }
        const int g0 = (bkh * 2) ^ (bn & 3), g1 = (bkh * 2 + 1) ^ (bn & 3);
        *(short8*)&Bss[buf][bn * 32 + g0 * 8] = v0;
        *(short8*)&Bss[buf][bn * 32 + g1 * 8] = v1;
    };

    auto compute = [&](int buf) {
        short8 af[4], bf[4];
#pragma unroll
        for (int mi = 0; mi < 4; ++mi) {
            const int m = wm * 64 + mi * 16 + l15;
            const int s = m & 7;
            const f32x4 x0 = *(const f32x4*)&Asf[buf][m * 32 + (((l4 * 2) ^ s) << 2)];
            const f32x4 x1 = *(const f32x4*)&Asf[buf][m * 32 + (((l4 * 2 + 1) ^ s) << 2)];
            short8 v;
#pragma unroll
            for (int j = 0; j < 4; ++j) { v[j] = f2bf(x0[j]); v[4 + j] = f2bf(x1[j]); }
            af[mi] = v;
        }
#pragma unroll
        for (int ni = 0; ni < 4; ++ni) {
            const int n = wn * 64 + ni * 16 + l15;
            bf[ni] = *(const short8*)&Bss[buf][n * 32 + ((l4 ^ (n & 3)) << 3)];
        }
#pragma unroll
        for (int mi = 0; mi < 4; ++mi)
#pragma unroll
            for (int ni = 0; ni < 4; ++ni)
                acc[mi][ni] = __builtin_amdgcn_mfma_f32_16x16x32_bf16(
                    af[mi], bf[ni], acc[mi][ni], 0, 0, 0);
    };

    // prologue
    stage_a(0, 0);
    load_b(0);
    write_b(0);
    __syncthreads();

    int buf = 0;
    for (int kt = 0; kt < NKT; ++kt) {
        const bool more = (kt + 1 < NKT);
        if (more) { stage_a(kt + 1, buf ^ 1); load_b(kt + 1); }
        compute(buf);
        if (more) write_b(buf ^ 1);   // vmcnt wait for breg covered by compute
        __syncthreads();              // drains gload_lds for buf^1
        buf ^= 1;
    }

    // epilogue: C/D layout col=lane&15, row=(lane>>4)*4+reg (m89-verified)
#pragma unroll
    for (int mi = 0; mi < 4; ++mi) {
        const int rbase = row0 + wm * 64 + mi * 16 + l4 * 4;
#pragma unroll
        for (int ni = 0; ni < 4; ++ni) {
            const int c = col0 + wn * 64 + ni * 16 + l15;
#pragma unroll
            for (int r = 0; r < 4; ++r)
                out[(size_t)(rbase + r) * Nd + c] = acc[mi][ni][r];
        }
    }
}

extern "C" void kernel_launch(void* const* d_in, const int* in_sizes, int n_in,
                              void* d_out, int out_size, void* d_ws, size_t ws_size,
                              hipStream_t stream) {
    const float* H = (const float*)d_in[0];
    const float* W = (const float*)d_in[1];
    const int* counts = (const int*)d_in[2];
    float* out = (float*)d_out;
    const int grid = (Tt / BM) * (Nd / BN);  // 512 blocks
    grouped_gemm_kernel<<<grid, 256, 0, stream>>>(H, W, counts, out);
}

// Round 4
// 39.218 us; speedup vs baseline: 86.0179x; 1.2272x over previous
//
#include <hip/hip_runtime.h>
#include <hip/hip_bf16.h>
#include <stdint.h>

typedef __attribute__((ext_vector_type(8))) short short8;
typedef __attribute__((ext_vector_type(4))) float f32x4;

constexpr int Tt = 8192, Kd = 1024, Nd = 1024, Gn = 8;
constexpr int BM = 128, BN = 256, BK = 64;
constexpr int NKT = Kd / BK; // 16 K-tiles

static __device__ __forceinline__ short f2bf(float x) {
    __hip_bfloat16 b = __float2bfloat16(x);
    return *reinterpret_cast<short*>(&b);
}

__global__ __launch_bounds__(512, 2)
void grouped_gemm_kernel(const float* __restrict__ H,
                         const float* __restrict__ W,
                         const int* __restrict__ counts,
                         float* __restrict__ out)
{
    // bf16 LDS, rows of 64 shorts = 128B (8 granules of 16B), slot = g ^ (row&7)
    __shared__ __align__(16) short As[2][BM * BK];   // 32 KB
    __shared__ __align__(16) short Bs[2][BN * BK];   // 64 KB

    const int tid = threadIdx.x;
    const int bid = blockIdx.x;
    const int swz = (bid & 7) * 32 + (bid >> 3);     // bijective XCD swizzle (256%8==0)
    const int mt = swz >> 2, nt = swz & 3;
    const int row0 = mt * BM, col0 = nt * BN;

    // expert id (cumsum boundaries are multiples of 128 -> no tile straddle)
    int g = 0;
    {
        int c = 0;
        for (int i = 0; i < Gn; ++i) { c += counts[i]; if (row0 >= c) g = i + 1; }
    }
    const float* __restrict__ Wg = W + (size_t)g * Kd * Nd;

    const int wid = tid >> 6, lane = tid & 63;
    const int wm = wid >> 2, wn = wid & 3;           // 2M x 4N waves, 64x64 each
    const int l15 = lane & 15, l4 = lane >> 4;

    // staging thread mapping
    const int ra = tid >> 2, ca = tid & 3;           // A: row ra, 16-float chunk ca
    const int nb = tid & 255, kh = tid >> 8;         // B: col nb, k-half kh

    f32x4 acc[4][4];
#pragma unroll
    for (int i = 0; i < 4; ++i)
#pragma unroll
        for (int j = 0; j < 4; ++j) acc[i][j] = (f32x4)0.0f;

    f32x4 av[4];      // A staging: 16 floats
    float bv[32];     // B staging: 32 strided floats (transpose in regs)

    auto load_a = [&](int kt) {
        const float* p = H + (size_t)(row0 + ra) * Kd + kt * BK + ca * 16;
#pragma unroll
        for (int j = 0; j < 4; ++j) av[j] = *(const f32x4*)(p + j * 4);
    };
    auto load_b = [&](int kt) {
        const float* p = Wg + (size_t)(kt * BK + kh * 32) * Nd + col0 + nb;
#pragma unroll
        for (int j = 0; j < 32; ++j) bv[j] = p[(size_t)j * Nd];
    };
    auto write_a = [&](int buf) {
        short8 v0, v1;
#pragma unroll
        for (int j = 0; j < 4; ++j) {
            v0[j] = f2bf(av[0][j]); v0[4 + j] = f2bf(av[1][j]);
            v1[j] = f2bf(av[2][j]); v1[4 + j] = f2bf(av[3][j]);
        }
        const int s = ra & 7;
        *(short8*)&As[buf][ra * 64 + (((ca * 2) ^ s) << 3)] = v0;
        *(short8*)&As[buf][ra * 64 + (((ca * 2 + 1) ^ s) << 3)] = v1;
    };
    auto write_b = [&](int buf) {
        const int s = nb & 7;
#pragma unroll
        for (int c = 0; c < 4; ++c) {
            short8 v;
#pragma unroll
            for (int j = 0; j < 8; ++j) v[j] = f2bf(bv[c * 8 + j]);
            *(short8*)&Bs[buf][nb * 64 + (((kh * 4 + c) ^ s) << 3)] = v;
        }
    };

    auto rd_a = [&](int buf, int mi, int ks) -> short8 {
        const int m = wm * 64 + mi * 16 + l15;
        return *(const short8*)&As[buf][m * 64 + (((ks * 4 + l4) ^ (m & 7)) << 3)];
    };
    auto rd_b = [&](int buf, int ni, int ks) -> short8 {
        const int n = wn * 64 + ni * 16 + l15;
        return *(const short8*)&Bs[buf][n * 64 + (((ks * 4 + l4) ^ (n & 7)) << 3)];
    };

    // prologue: stage tile 0 into buf 0
    load_a(0); load_b(0);
    write_a(0); write_b(0);
    asm volatile("s_waitcnt lgkmcnt(0)" ::: "memory");
    __builtin_amdgcn_s_barrier();

    int buf = 0;
    for (int kt = 0; kt < NKT; ++kt) {
        const bool more = (kt + 1 < NKT);
        if (more) { load_a(kt + 1); load_b(kt + 1); }  // issue early (covers HBM lat)

        short8 a0[2][2], a1[2][2], b0[2][2], b1[2][2]; // [idx][ks]

        // q0: (m-half 0, n-half 0)
#pragma unroll
        for (int i = 0; i < 2; ++i)
#pragma unroll
            for (int ks = 0; ks < 2; ++ks) { a0[i][ks] = rd_a(buf, i, ks); b0[i][ks] = rd_b(buf, i, ks); }
        __builtin_amdgcn_s_setprio(1);
#pragma unroll
        for (int mi = 0; mi < 2; ++mi)
#pragma unroll
            for (int ni = 0; ni < 2; ++ni)
#pragma unroll
                for (int ks = 0; ks < 2; ++ks)
                    acc[mi][ni] = __builtin_amdgcn_mfma_f32_16x16x32_bf16(
                        a0[mi][ks], b0[ni][ks], acc[mi][ni], 0, 0, 0);
        __builtin_amdgcn_s_setprio(0);

        // q1: (m-half 1, n-half 0)
#pragma unroll
        for (int i = 0; i < 2; ++i)
#pragma unroll
            for (int ks = 0; ks < 2; ++ks) a1[i][ks] = rd_a(buf, 2 + i, ks);
        __builtin_amdgcn_s_setprio(1);
#pragma unroll
        for (int mi = 0; mi < 2; ++mi)
#pragma unroll
            for (int ni = 0; ni < 2; ++ni)
#pragma unroll
                for (int ks = 0; ks < 2; ++ks)
                    acc[2 + mi][ni] = __builtin_amdgcn_mfma_f32_16x16x32_bf16(
                        a1[mi][ks], b0[ni][ks], acc[2 + mi][ni], 0, 0, 0);
        __builtin_amdgcn_s_setprio(0);

        // mid-tile: convert + write next tile (compiler inserts counted vmcnt here)
        if (more) { write_a(buf ^ 1); write_b(buf ^ 1); }

        // q2: (m-half 1, n-half 1)
#pragma unroll
        for (int i = 0; i < 2; ++i)
#pragma unroll
            for (int ks = 0; ks < 2; ++ks) b1[i][ks] = rd_b(buf, 2 + i, ks);
        __builtin_amdgcn_s_setprio(1);
#pragma unroll
        for (int mi = 0; mi < 2; ++mi)
#pragma unroll
            for (int ni = 0; ni < 2; ++ni)
#pragma unroll
                for (int ks = 0; ks < 2; ++ks)
                    acc[2 + mi][2 + ni] = __builtin_amdgcn_mfma_f32_16x16x32_bf16(
                        a1[mi][ks], b1[ni][ks], acc[2 + mi][2 + ni], 0, 0, 0);
        __builtin_amdgcn_s_setprio(0);

        // q3: (m-half 0, n-half 1) — reuse a0, b1
        __builtin_amdgcn_s_setprio(1);
#pragma unroll
        for (int mi = 0; mi < 2; ++mi)
#pragma unroll
            for (int ni = 0; ni < 2; ++ni)
#pragma unroll
                for (int ks = 0; ks < 2; ++ks)
                    acc[mi][2 + ni] = __builtin_amdgcn_mfma_f32_16x16x32_bf16(
                        a0[mi][ks], b1[ni][ks], acc[mi][2 + ni], 0, 0, 0);
        __builtin_amdgcn_s_setprio(0);

        // one raw barrier per K-tile: my ds_writes drained, then all waves cross.
        // No vmcnt drain here — next-tile loads stay in flight (T4).
        asm volatile("s_waitcnt lgkmcnt(0)" ::: "memory");
        __builtin_amdgcn_s_barrier();
        buf ^= 1;
    }

    // epilogue: C/D layout col=lane&15, row=(lane>>4)*4+reg
#pragma unroll
    for (int mi = 0; mi < 4; ++mi) {
        const int rbase = row0 + wm * 64 + mi * 16 + l4 * 4;
#pragma unroll
        for (int ni = 0; ni < 4; ++ni) {
            const int c = col0 + wn * 64 + ni * 16 + l15;
#pragma unroll
            for (int r = 0; r < 4; ++r)
                out[(size_t)(rbase + r) * Nd + c] = acc[mi][ni][r];
        }
    }
}

extern "C" void kernel_launch(void* const* d_in, const int* in_sizes, int n_in,
                              void* d_out, int out_size, void* d_ws, size_t ws_size,
                              hipStream_t stream) {
    const float* H = (const float*)d_in[0];
    const float* W = (const float*)d_in[1];
    const int* counts = (const int*)d_in[2];
    float* out = (float*)d_out;
    const int grid = (Tt / BM) * (Nd / BN);  // 64 * 4 = 256 blocks = 1/CU
    grouped_gemm_kernel<<<grid, 512, 0, stream>>>(H, W, counts, out);
}